// Round 6
// baseline (283.064 us; speedup 1.0000x reference)
//
#include <hip/hip_runtime.h>
#include <hip/hip_bf16.h>
#include <hip/hip_fp8.h>

// Problem constants (fixed by reference): N=4096, D=256, T=0.5, EPS=1e-8
#define PN   4096
#define PN2  8192
#define PD   256                       // also row stride in BYTES for fp8 zn
#define TILE 128
#define BK   128                       // fp8 k-elems per slab = 128 B/row
#define NBLK (PN2 / TILE)              // 64 tile-blocks per dim
#define NTRI (NBLK * (NBLK + 1) / 2)   // 2080 upper-tri blocks (2080 % 8 == 0)

typedef __attribute__((ext_vector_type(4))) float f32x4;
typedef const __attribute__((address_space(1))) void* gas_ptr;
typedef __attribute__((address_space(3))) void* las_ptr;

// ---------------------------------------------------------------------------
// Shared helpers (identical math to the proven R5 kernel)
// ---------------------------------------------------------------------------
__device__ __forceinline__ void tri_decode(int idx, int& bi, int& bj) {
  bj = (int)((sqrtf(8.0f * (float)idx + 1.0f) - 1.0f) * 0.5f);
  while ((bj + 1) * (bj + 2) / 2 <= idx) ++bj;
  while (bj * (bj + 1) / 2 > idx) --bj;
  bi = idx - bj * (bj + 1) / 2;
}

__device__ __forceinline__ void stage_slab(
    const unsigned char* __restrict__ zn8, char* As, char* Bs,
    int rowBase, int colBase, int kt, int wave, int subrow, int slot,
    bool diagBlk) {
  #pragma unroll
  for (int p = 0; p < 4; ++p) {
    int issue = wave * 4 + p;            // 0..15, wave-uniform
    int rr = issue * 8 + subrow;         // tile row 0..127
    int cc = slot ^ (rr & 7);            // swizzled 16B-granule
    const unsigned char* ga = zn8 + (size_t)(rowBase + rr) * PD + kt * BK + cc * 16;
    __builtin_amdgcn_global_load_lds((gas_ptr)ga, (las_ptr)(As + issue * 1024), 16, 0, 0);
    if (!diagBlk) {
      const unsigned char* gb = zn8 + (size_t)(colBase + rr) * PD + kt * BK + cc * 16;
      __builtin_amdgcn_global_load_lds((gas_ptr)gb, (las_ptr)(Bs + issue * 1024), 16, 0, 0);
    }
  }
}

// ---------------------------------------------------------------------------
// ABLATION kernel (instrumentation only; results dumped to scratch).
// V0: stage+barriers | V1: +ds_read+MFMA | V2: full incl. epilogue.
// Internal x3 repeat so each dispatch ranks above the ~43us fill rows.
// ---------------------------------------------------------------------------
template<int V>
__global__ __launch_bounds__(256) void ablate_kernel(
    const unsigned char* __restrict__ zn8, float* __restrict__ dump) {
  __shared__ char lds[2 * TILE * BK];   // 32 KiB: As then Bs
  __shared__ float rowacc[TILE];
  __shared__ float colacc[TILE];
  char* As = lds;
  char* Bs = lds + TILE * BK;

  const int tid = threadIdx.x;
  if (tid < TILE) { rowacc[tid] = 0.0f; colacc[tid] = 0.0f; }

  const int idx = (int)((blockIdx.x & 7) * (NTRI / 8) + (blockIdx.x >> 3));
  int bi, bj;
  tri_decode(idx, bi, bj);
  const bool diagBlk = (bi == bj);

  const int wave = tid >> 6;
  const int lane = tid & 63;
  const int quad = lane >> 4;
  const int c16  = lane & 15;
  const int rowBase = bi * TILE;
  const int colBase = bj * TILE;
  const int waveRow = (wave >> 1) * 64;
  const int waveCol = (wave & 1) * 64;
  const int subrow = lane >> 3;
  const int slot   = lane & 7;
  const char* BsEff = diagBlk ? As : Bs;

  float keep = 0.0f;

  for (int rep = 0; rep < 3; ++rep) {
    f32x4 acc[4][4];
    #pragma unroll
    for (int i = 0; i < 4; ++i)
      #pragma unroll
      for (int j = 0; j < 4; ++j)
        acc[i][j] = (f32x4){0.f, 0.f, 0.f, 0.f};

    for (int kt = 0; kt < PD / BK; ++kt) {
      if (kt | rep) __syncthreads();   // protect LDS before overwrite
      stage_slab(zn8, As, Bs, rowBase, colBase, kt, wave, subrow, slot, diagBlk);
      __syncthreads();                 // vmcnt(0) drain + barrier

      if (V >= 1) {
        #pragma unroll
        for (int ki = 0; ki < 4; ++ki) {
          const int G  = ki * 2 + (quad >> 1);
          const int h8 = (quad & 1) * 8;
          long a[4], b[4];
          #pragma unroll
          for (int mi = 0; mi < 4; ++mi) {
            int r = waveRow + mi * 16 + c16;
            a[mi] = *(const long*)(As + r * 128 + (((G ^ (r & 7)) << 4) + h8));
          }
          #pragma unroll
          for (int ni = 0; ni < 4; ++ni) {
            int r = waveCol + ni * 16 + c16;
            b[ni] = *(const long*)(BsEff + r * 128 + (((G ^ (r & 7)) << 4) + h8));
          }
          #pragma unroll
          for (int mi = 0; mi < 4; ++mi)
            #pragma unroll
            for (int ni = 0; ni < 4; ++ni)
              acc[mi][ni] = __builtin_amdgcn_mfma_f32_16x16x32_fp8_fp8(a[mi], b[ni], acc[mi][ni], 0, 0, 0);
        }
      }
    }

    if (V >= 2) {
      float colsum[4] = {0.f, 0.f, 0.f, 0.f};
      #pragma unroll
      for (int mi = 0; mi < 4; ++mi) {
        int lrow = waveRow + mi * 16 + quad * 4;
        float rs[4] = {0.f, 0.f, 0.f, 0.f};
        #pragma unroll
        for (int ni = 0; ni < 4; ++ni) {
          int gcol = colBase + waveCol + ni * 16 + c16;
          #pragma unroll
          for (int t = 0; t < 4; ++t) {
            int grow = rowBase + lrow + t;
            float e = __expf(2.0f * acc[mi][ni][t]);
            if (diagBlk && gcol == grow) e = 0.0f;
            rs[t] += e;
            colsum[ni] += e;
          }
        }
        #pragma unroll
        for (int t = 0; t < 4; ++t) {
          #pragma unroll
          for (int off = 1; off <= 8; off <<= 1) rs[t] += __shfl_xor(rs[t], off, 64);
        }
        if (c16 == 0) {
          #pragma unroll
          for (int t = 0; t < 4; ++t) atomicAdd(&rowacc[lrow + t], rs[t]);
        }
      }
      if (!diagBlk) {
        #pragma unroll
        for (int ni = 0; ni < 4; ++ni) {
          float cs = colsum[ni];
          cs += __shfl_xor(cs, 16, 64);
          cs += __shfl_xor(cs, 32, 64);
          if (quad == 0) atomicAdd(&colacc[waveCol + ni * 16 + c16], cs);
        }
      }
    } else if (V == 1) {
      #pragma unroll
      for (int mi = 0; mi < 4; ++mi)
        #pragma unroll
        for (int ni = 0; ni < 4; ++ni)
          #pragma unroll
          for (int t = 0; t < 4; ++t) keep += acc[mi][ni][t];   // keep acc live
    }
  }

  if (V == 1) dump[(size_t)blockIdx.x * 256 + tid] = keep;
  if (V >= 2) {
    __syncthreads();
    if (tid < TILE) {
      dump[(size_t)bj * PN2 + rowBase + tid] = rowacc[tid];
      if (!diagBlk) dump[(size_t)bi * PN2 + colBase + tid] = colacc[tid];
    }
  }
}

// ---------------------------------------------------------------------------
// Kernel 1: pair-wise normalize (unchanged from R5, proven).
// ---------------------------------------------------------------------------
__global__ __launch_bounds__(256) void normalize_kernel(
    const float* __restrict__ zi, const float* __restrict__ zj,
    unsigned char* __restrict__ zn8, float* __restrict__ pos,
    float* __restrict__ wlws, unsigned* __restrict__ ticket) {
  const int wave = threadIdx.x >> 6;
  const int lane = threadIdx.x & 63;
  const int r = blockIdx.x * 4 + wave;           // pair id 0..4095
  float4 a = *(const float4*)(zi + (size_t)r * PD + lane * 4);
  float4 b = *(const float4*)(zj + (size_t)r * PD + lane * 4);
  float si = a.x * a.x + a.y * a.y + a.z * a.z + a.w * a.w;
  float sj = b.x * b.x + b.y * b.y + b.z * b.z + b.w * b.w;
  float d  = a.x * b.x + a.y * b.y + a.z * b.z + a.w * b.w;
  #pragma unroll
  for (int off = 32; off >= 1; off >>= 1) {
    si += __shfl_xor(si, off, 64);
    sj += __shfl_xor(sj, off, 64);
    d  += __shfl_xor(d,  off, 64);
  }
  float ni = fmaxf(sqrtf(si), 1e-8f);
  float nj = fmaxf(sqrtf(sj), 1e-8f);
  if (lane == 0) {
    float p = d / (ni * nj);
    pos[r] = p;
    pos[r + PN] = p;
  }
  float ia = 1.0f / ni, ib = 1.0f / nj;
  union { unsigned u; unsigned char c[4]; } pa, pb;
  pa.c[0] = __hip_cvt_float_to_fp8(a.x * ia, __HIP_SATFINITE, __HIP_E4M3);
  pa.c[1] = __hip_cvt_float_to_fp8(a.y * ia, __HIP_SATFINITE, __HIP_E4M3);
  pa.c[2] = __hip_cvt_float_to_fp8(a.z * ia, __HIP_SATFINITE, __HIP_E4M3);
  pa.c[3] = __hip_cvt_float_to_fp8(a.w * ia, __HIP_SATFINITE, __HIP_E4M3);
  pb.c[0] = __hip_cvt_float_to_fp8(b.x * ib, __HIP_SATFINITE, __HIP_E4M3);
  pb.c[1] = __hip_cvt_float_to_fp8(b.y * ib, __HIP_SATFINITE, __HIP_E4M3);
  pb.c[2] = __hip_cvt_float_to_fp8(b.z * ib, __HIP_SATFINITE, __HIP_E4M3);
  pb.c[3] = __hip_cvt_float_to_fp8(b.w * ib, __HIP_SATFINITE, __HIP_E4M3);
  *(unsigned*)(zn8 + (size_t)r * PD + lane * 4) = pa.u;
  *(unsigned*)(zn8 + (size_t)(r + PN) * PD + lane * 4) = pb.u;
  if (blockIdx.x == 0 && threadIdx.x == 0) {
    wlws[0] = 0.0f; wlws[1] = 0.0f; *ticket = 0u;
  }
}

// ---------------------------------------------------------------------------
// Kernel 2: REAL simsum (unchanged from R5, passed absmax 0.0).
// ---------------------------------------------------------------------------
__global__ __launch_bounds__(256) void simsum_kernel(
    const unsigned char* __restrict__ zn8, float* __restrict__ rowpart) {
  __shared__ char lds[2 * TILE * BK];
  __shared__ float rowacc[TILE];
  __shared__ float colacc[TILE];
  char* As = lds;
  char* Bs = lds + TILE * BK;

  const int tid = threadIdx.x;
  if (tid < TILE) { rowacc[tid] = 0.0f; colacc[tid] = 0.0f; }

  const int idx = (int)((blockIdx.x & 7) * (NTRI / 8) + (blockIdx.x >> 3));
  int bi, bj;
  tri_decode(idx, bi, bj);
  const bool diagBlk = (bi == bj);

  const int wave = tid >> 6;
  const int lane = tid & 63;
  const int quad = lane >> 4;
  const int c16  = lane & 15;
  const int rowBase = bi * TILE;
  const int colBase = bj * TILE;
  const int waveRow = (wave >> 1) * 64;
  const int waveCol = (wave & 1) * 64;
  const int subrow = lane >> 3;
  const int slot   = lane & 7;
  const char* BsEff = diagBlk ? As : Bs;

  f32x4 acc[4][4];
  #pragma unroll
  for (int i = 0; i < 4; ++i)
    #pragma unroll
    for (int j = 0; j < 4; ++j)
      acc[i][j] = (f32x4){0.f, 0.f, 0.f, 0.f};

  for (int kt = 0; kt < PD / BK; ++kt) {
    if (kt) __syncthreads();
    stage_slab(zn8, As, Bs, rowBase, colBase, kt, wave, subrow, slot, diagBlk);
    __syncthreads();

    #pragma unroll
    for (int ki = 0; ki < 4; ++ki) {
      const int G  = ki * 2 + (quad >> 1);
      const int h8 = (quad & 1) * 8;
      long a[4], b[4];
      #pragma unroll
      for (int mi = 0; mi < 4; ++mi) {
        int r = waveRow + mi * 16 + c16;
        a[mi] = *(const long*)(As + r * 128 + (((G ^ (r & 7)) << 4) + h8));
      }
      #pragma unroll
      for (int ni = 0; ni < 4; ++ni) {
        int r = waveCol + ni * 16 + c16;
        b[ni] = *(const long*)(BsEff + r * 128 + (((G ^ (r & 7)) << 4) + h8));
      }
      #pragma unroll
      for (int mi = 0; mi < 4; ++mi)
        #pragma unroll
        for (int ni = 0; ni < 4; ++ni)
          acc[mi][ni] = __builtin_amdgcn_mfma_f32_16x16x32_fp8_fp8(a[mi], b[ni], acc[mi][ni], 0, 0, 0);
    }
  }

  float colsum[4] = {0.f, 0.f, 0.f, 0.f};
  #pragma unroll
  for (int mi = 0; mi < 4; ++mi) {
    int lrow = waveRow + mi * 16 + quad * 4;
    float rs[4] = {0.f, 0.f, 0.f, 0.f};
    #pragma unroll
    for (int ni = 0; ni < 4; ++ni) {
      int gcol = colBase + waveCol + ni * 16 + c16;
      #pragma unroll
      for (int t = 0; t < 4; ++t) {
        int grow = rowBase + lrow + t;
        float e = __expf(2.0f * acc[mi][ni][t]);
        if (diagBlk && gcol == grow) e = 0.0f;
        rs[t] += e;
        colsum[ni] += e;
      }
    }
    #pragma unroll
    for (int t = 0; t < 4; ++t) {
      #pragma unroll
      for (int off = 1; off <= 8; off <<= 1) rs[t] += __shfl_xor(rs[t], off, 64);
    }
    if (c16 == 0) {
      #pragma unroll
      for (int t = 0; t < 4; ++t) atomicAdd(&rowacc[lrow + t], rs[t]);
    }
  }
  if (!diagBlk) {
    #pragma unroll
    for (int ni = 0; ni < 4; ++ni) {
      float cs = colsum[ni];
      cs += __shfl_xor(cs, 16, 64);
      cs += __shfl_xor(cs, 32, 64);
      if (quad == 0) atomicAdd(&colacc[waveCol + ni * 16 + c16], cs);
    }
  }

  __syncthreads();
  if (tid < TILE) {
    rowpart[(size_t)bj * PN2 + rowBase + tid] = rowacc[tid];
    if (!diagBlk)
      rowpart[(size_t)bi * PN2 + colBase + tid] = colacc[tid];
  }
}

// ---------------------------------------------------------------------------
// Kernel 3: finalize (unchanged from R5).
// ---------------------------------------------------------------------------
__global__ __launch_bounds__(256) void finalize_kernel(
    const float* __restrict__ rowpart, const float* __restrict__ pos,
    const float* __restrict__ w, float* __restrict__ wlws,
    unsigned* __restrict__ ticket, float* __restrict__ out) {
  const int tid = threadIdx.x;
  const int r = blockIdx.x * 256 + tid;
  float s = 0.0f;
  #pragma unroll
  for (int x = 0; x < NBLK; ++x) s += rowpart[(size_t)x * PN2 + r];
  float li = logf(s) - 2.0f * pos[r];
  float wi = w[r & (PN - 1)];
  float wl = wi * li, ws = wi;
  #pragma unroll
  for (int off = 32; off >= 1; off >>= 1) {
    wl += __shfl_xor(wl, off, 64);
    ws += __shfl_xor(ws, off, 64);
  }
  __shared__ float pl[4], pw[4];
  const int lane = tid & 63, wv = tid >> 6;
  if (lane == 0) { pl[wv] = wl; pw[wv] = ws; }
  __syncthreads();
  if (tid == 0) {
    atomicAdd(&wlws[0], pl[0] + pl[1] + pl[2] + pl[3]);
    atomicAdd(&wlws[1], pw[0] + pw[1] + pw[2] + pw[3]);
    __threadfence();
    if (atomicAdd(ticket, 1u) == 31) {
      float a = atomicAdd(&wlws[0], 0.0f);
      float b = atomicAdd(&wlws[1], 0.0f);
      out[0] = a / b;
    }
  }
}

// ---------------------------------------------------------------------------
extern "C" void kernel_launch(void* const* d_in, const int* in_sizes, int n_in,
                              void* d_out, int out_size, void* d_ws, size_t ws_size,
                              hipStream_t stream) {
  const float* zi = (const float*)d_in[0];
  const float* zj = (const float*)d_in[1];
  const float* w  = (const float*)d_in[2];
  float* out = (float*)d_out;

  // Workspace: zn8 u8[8192*256]=2MiB | rowpart f32[64][8192]=2MiB |
  //            pos f32[8192] | wlws f32[2] | ticket u32 | ... | dump @32MiB
  unsigned char* zn8 = (unsigned char*)d_ws;
  float* rowpart = (float*)((char*)d_ws + (size_t)PN2 * PD);
  float* pos     = rowpart + (size_t)NBLK * PN2;
  float* wlws    = pos + PN2;
  unsigned* ticket = (unsigned*)(wlws + 2);
  float* dump0 = (float*)((char*)d_ws + (32u << 20));
  float* dump1 = (float*)((char*)d_ws + (40u << 20));
  float* dump2 = (float*)((char*)d_ws + (48u << 20));

  // --- instrumentation dispatches (read poisoned zn8; outputs unused) ---
  ablate_kernel<0><<<NTRI, 256, 0, stream>>>(zn8, dump0);
  ablate_kernel<1><<<NTRI, 256, 0, stream>>>(zn8, dump1);
  ablate_kernel<2><<<NTRI, 256, 0, stream>>>(zn8, dump2);

  // --- real pipeline (unchanged from R5, passed) ---
  normalize_kernel<<<PN / 4, 256, 0, stream>>>(zi, zj, zn8, pos, wlws, ticket);
  simsum_kernel<<<NTRI, 256, 0, stream>>>(zn8, rowpart);
  finalize_kernel<<<32, 256, 0, stream>>>(rowpart, pos, w, wlws, ticket, out);
}

// Round 7
// 103.096 us; speedup vs baseline: 2.7456x; 2.7456x over previous
//
#include <hip/hip_runtime.h>
#include <hip/hip_bf16.h>
#include <hip/hip_fp8.h>

// Problem constants (fixed by reference): N=4096, D=256, T=0.5, EPS=1e-8
#define PN   4096
#define PN2  8192
#define PD   256                       // bytes per fp8 zn row == K
#define TILE 256
#define NBLK (PN2 / TILE)              // 32 tile-blocks per dim
#define NTRI (NBLK * (NBLK + 1) / 2)   // 528 upper-tri blocks (528 % 8 == 0)

typedef __attribute__((ext_vector_type(4))) float f32x4;
typedef const __attribute__((address_space(1))) void* gas_ptr;
typedef __attribute__((address_space(3))) void* las_ptr;

__device__ __forceinline__ void tri_decode(int idx, int& bi, int& bj) {
  bj = (int)((sqrtf(8.0f * (float)idx + 1.0f) - 1.0f) * 0.5f);
  while ((bj + 1) * (bj + 2) / 2 <= idx) ++bj;
  while (bj * (bj + 1) / 2 > idx) --bj;
  bi = idx - bj * (bj + 1) / 2;
}

// ---------------------------------------------------------------------------
// Kernel 1: pair-wise normalize (unchanged from R5, passed absmax 0.0).
// One WAVE per pair (r, r+N): fp32 norms + dot -> exact fp32 positives;
// writes both rows of zn as OCP e4m3 (2 MiB total, L2-resident).
// ---------------------------------------------------------------------------
__global__ __launch_bounds__(256) void normalize_kernel(
    const float* __restrict__ zi, const float* __restrict__ zj,
    unsigned char* __restrict__ zn8, float* __restrict__ pos,
    float* __restrict__ wlws, unsigned* __restrict__ ticket) {
  const int wave = threadIdx.x >> 6;
  const int lane = threadIdx.x & 63;
  const int r = blockIdx.x * 4 + wave;           // pair id 0..4095
  float4 a = *(const float4*)(zi + (size_t)r * PD + lane * 4);
  float4 b = *(const float4*)(zj + (size_t)r * PD + lane * 4);
  float si = a.x * a.x + a.y * a.y + a.z * a.z + a.w * a.w;
  float sj = b.x * b.x + b.y * b.y + b.z * b.z + b.w * b.w;
  float d  = a.x * b.x + a.y * b.y + a.z * b.z + a.w * b.w;
  #pragma unroll
  for (int off = 32; off >= 1; off >>= 1) {
    si += __shfl_xor(si, off, 64);
    sj += __shfl_xor(sj, off, 64);
    d  += __shfl_xor(d,  off, 64);
  }
  float ni = fmaxf(sqrtf(si), 1e-8f);
  float nj = fmaxf(sqrtf(sj), 1e-8f);
  if (lane == 0) {
    float p = d / (ni * nj);
    pos[r] = p;
    pos[r + PN] = p;
  }
  float ia = 1.0f / ni, ib = 1.0f / nj;
  union { unsigned u; unsigned char c[4]; } pa, pb;
  pa.c[0] = __hip_cvt_float_to_fp8(a.x * ia, __HIP_SATFINITE, __HIP_E4M3);
  pa.c[1] = __hip_cvt_float_to_fp8(a.y * ia, __HIP_SATFINITE, __HIP_E4M3);
  pa.c[2] = __hip_cvt_float_to_fp8(a.z * ia, __HIP_SATFINITE, __HIP_E4M3);
  pa.c[3] = __hip_cvt_float_to_fp8(a.w * ia, __HIP_SATFINITE, __HIP_E4M3);
  pb.c[0] = __hip_cvt_float_to_fp8(b.x * ib, __HIP_SATFINITE, __HIP_E4M3);
  pb.c[1] = __hip_cvt_float_to_fp8(b.y * ib, __HIP_SATFINITE, __HIP_E4M3);
  pb.c[2] = __hip_cvt_float_to_fp8(b.z * ib, __HIP_SATFINITE, __HIP_E4M3);
  pb.c[3] = __hip_cvt_float_to_fp8(b.w * ib, __HIP_SATFINITE, __HIP_E4M3);
  *(unsigned*)(zn8 + (size_t)r * PD + lane * 4) = pa.u;
  *(unsigned*)(zn8 + (size_t)(r + PN) * PD + lane * 4) = pb.u;
  if (blockIdx.x == 0 && threadIdx.x == 0) {
    wlws[0] = 0.0f; wlws[1] = 0.0f; *ticket = 0u;
  }
}

// ---------------------------------------------------------------------------
// Kernel 2: sim = zn @ zn^T fp8, upper-tri 256x256 tiles. WHOLE-TILE-IN-LDS:
// fp8 K=256 is 256 B/row, so A panel (64K) + B panel (64K) both fit LDS.
// Structure per tile: stage once (128 x 1KiB DMA) -> ONE barrier -> 8 k-steps
// of pure ds_read+MFMA (256 MFMA/wave) -> epilogue. No intra-tile phase
// alternation (the m233 2-phase stall, 2080x paid before, is gone).
// 8 waves (512 thr), wave grid 2M x 4N, per-wave 128x64 output (acc 128 VGPR).
// Swizzle: LDS granule g_pos of row r holds source granule g_pos ^ (r&15)
// (16 granules/row -> each 16-lane ds_read group hits 16 distinct granules,
// 2-way bank alias max = free; fixes R5's 6.39M 4-way conflicts).
// Epilogue: LDS accumulation, unique-writer partial stores (proof as before):
//   row-partials of (bi,bj) -> rowpart[bj][bi*256..), col -> rowpart[bi][bj*256..)
// ---------------------------------------------------------------------------
__global__ __launch_bounds__(512, 2) void simsum_kernel(
    const unsigned char* __restrict__ zn8, float* __restrict__ rowpart) {
  __shared__ char As[TILE * PD];        // 64 KiB
  __shared__ char Bs[TILE * PD];        // 64 KiB
  __shared__ float rowacc[TILE];
  __shared__ float colacc[TILE];

  const int tid = threadIdx.x;
  if (tid < TILE) { rowacc[tid] = 0.0f; colacc[tid] = 0.0f; }

  // XCD swizzle (bijective, 528 % 8 == 0)
  const int idx = (int)((blockIdx.x & 7) * (NTRI / 8) + (blockIdx.x >> 3));
  int bi, bj;
  tri_decode(idx, bi, bj);
  const bool diagBlk = (bi == bj);

  const int wave = tid >> 6;           // 0..7
  const int lane = tid & 63;
  const int quad = lane >> 4;
  const int c16  = lane & 15;
  const int rowBase = bi * TILE;
  const int colBase = bj * TILE;
  const int waveRow = (wave >> 2) * 128;   // 0,128
  const int waveCol = (wave & 3) * 64;     // 0,64,128,192

  // ---- stage the WHOLE tile once: 64 issues A (+64 B), 8 (+8) per wave ----
  // issue i writes LDS rows 4i..4i+3 linearly; lane supplies the swizzled
  // global source granule (16B granularity, rule #21 both-sides pattern).
  #pragma unroll
  for (int p = 0; p < 8; ++p) {
    int issue = wave * 8 + p;            // 0..63, wave-uniform
    int rr = issue * 4 + quad;           // tile row 0..255
    int gs = c16 ^ (rr & 15);            // source granule for LDS slot c16
    const unsigned char* ga = zn8 + (size_t)(rowBase + rr) * PD + gs * 16;
    __builtin_amdgcn_global_load_lds((gas_ptr)ga, (las_ptr)(As + issue * 1024), 16, 0, 0);
    if (!diagBlk) {
      const unsigned char* gb = zn8 + (size_t)(colBase + rr) * PD + gs * 16;
      __builtin_amdgcn_global_load_lds((gas_ptr)gb, (las_ptr)(Bs + issue * 1024), 16, 0, 0);
    }
  }
  __syncthreads();   // the ONLY stage barrier per tile (vmcnt(0) drain)

  const char* BsEff = diagBlk ? As : Bs;

  f32x4 acc[8][4];
  #pragma unroll
  for (int i = 0; i < 8; ++i)
    #pragma unroll
    for (int j = 0; j < 4; ++j)
      acc[i][j] = (f32x4){0.f, 0.f, 0.f, 0.f};

  #pragma unroll
  for (int ki = 0; ki < 8; ++ki) {       // 8 x k=32 fp8 MFMA steps, no sync
    // lane's 8 fp8: k = ki*32 + quad*8 + j -> granule G, half h8
    const int G  = ki * 2 + (quad >> 1);     // 0..15
    const int h8 = (quad & 1) * 8;
    long b[4];
    #pragma unroll
    for (int ni = 0; ni < 4; ++ni) {
      int r = waveCol + ni * 16 + c16;       // B "row" of zn = sim column n
      b[ni] = *(const long*)(BsEff + r * 256 + (((G ^ (r & 15)) << 4) + h8));
    }
    #pragma unroll
    for (int mi = 0; mi < 8; ++mi) {
      int r = waveRow + mi * 16 + c16;       // A row: m = lane&15
      long a = *(const long*)(As + r * 256 + (((G ^ (r & 15)) << 4) + h8));
      #pragma unroll
      for (int ni = 0; ni < 4; ++ni)
        acc[mi][ni] = __builtin_amdgcn_mfma_f32_16x16x32_fp8_fp8(a, b[ni], acc[mi][ni], 0, 0, 0);
    }
  }

  // Epilogue (V2-V1 ablation: ~free). C/D layout: col=lane&15, row=quad*4+reg.
  float colsum[4] = {0.f, 0.f, 0.f, 0.f};
  #pragma unroll
  for (int mi = 0; mi < 8; ++mi) {
    int lrow = waveRow + mi * 16 + quad * 4;      // local row 0..255
    float rs[4] = {0.f, 0.f, 0.f, 0.f};
    #pragma unroll
    for (int ni = 0; ni < 4; ++ni) {
      int gcol = colBase + waveCol + ni * 16 + c16;
      #pragma unroll
      for (int t = 0; t < 4; ++t) {
        int grow = rowBase + lrow + t;
        float e = __expf(2.0f * acc[mi][ni][t]);    // exp(sim / T), T=0.5
        if (diagBlk && gcol == grow) e = 0.0f;      // mask diagonal
        rs[t] += e;
        colsum[ni] += e;
      }
    }
    #pragma unroll
    for (int t = 0; t < 4; ++t) {
      #pragma unroll
      for (int off = 1; off <= 8; off <<= 1) rs[t] += __shfl_xor(rs[t], off, 64);
    }
    if (c16 == 0) {                                  // LDS atomics: per-CU, cheap
      #pragma unroll
      for (int t = 0; t < 4; ++t) atomicAdd(&rowacc[lrow + t], rs[t]);
    }
  }
  if (!diagBlk) {   // column contributions = mirrored rows (symmetry)
    #pragma unroll
    for (int ni = 0; ni < 4; ++ni) {
      float cs = colsum[ni];
      cs += __shfl_xor(cs, 16, 64);
      cs += __shfl_xor(cs, 32, 64);
      if (quad == 0) atomicAdd(&colacc[waveCol + ni * 16 + c16], cs);
    }
  }

  __syncthreads();                // all LDS accumulation done
  if (tid < TILE) {               // plain stores, unique writers (see header)
    rowpart[(size_t)bj * PN2 + rowBase + tid] = rowacc[tid];
    if (!diagBlk)
      rowpart[(size_t)bi * PN2 + colBase + tid] = colacc[tid];
  }
}

// ---------------------------------------------------------------------------
// Kernel 3: rowsum[r] = sum_x rowpart[x][r]; loss_r = log(rowsum)-2*pos;
// out = sum(w*loss)/sum(w). 32 blocks x 256 threads, 1 row/thread.
// ---------------------------------------------------------------------------
__global__ __launch_bounds__(256) void finalize_kernel(
    const float* __restrict__ rowpart, const float* __restrict__ pos,
    const float* __restrict__ w, float* __restrict__ wlws,
    unsigned* __restrict__ ticket, float* __restrict__ out) {
  const int tid = threadIdx.x;
  const int r = blockIdx.x * 256 + tid;
  float s = 0.0f;
  #pragma unroll
  for (int x = 0; x < NBLK; ++x) s += rowpart[(size_t)x * PN2 + r];
  float li = logf(s) - 2.0f * pos[r];
  float wi = w[r & (PN - 1)];
  float wl = wi * li, ws = wi;
  #pragma unroll
  for (int off = 32; off >= 1; off >>= 1) {
    wl += __shfl_xor(wl, off, 64);
    ws += __shfl_xor(ws, off, 64);
  }
  __shared__ float pl[4], pw[4];
  const int lane = tid & 63, wv = tid >> 6;
  if (lane == 0) { pl[wv] = wl; pw[wv] = ws; }
  __syncthreads();
  if (tid == 0) {
    atomicAdd(&wlws[0], pl[0] + pl[1] + pl[2] + pl[3]);
    atomicAdd(&wlws[1], pw[0] + pw[1] + pw[2] + pw[3]);
    __threadfence();
    if (atomicAdd(ticket, 1u) == 31) {      // last of 32 blocks
      float a = atomicAdd(&wlws[0], 0.0f);  // coherent re-read
      float b = atomicAdd(&wlws[1], 0.0f);
      out[0] = a / b;
    }
  }
}

// ---------------------------------------------------------------------------
extern "C" void kernel_launch(void* const* d_in, const int* in_sizes, int n_in,
                              void* d_out, int out_size, void* d_ws, size_t ws_size,
                              hipStream_t stream) {
  const float* zi = (const float*)d_in[0];
  const float* zj = (const float*)d_in[1];
  const float* w  = (const float*)d_in[2];
  float* out = (float*)d_out;

  // Workspace: zn8 u8[8192*256]=2MiB | rowpart f32[32][8192]=1MiB |
  //            pos f32[8192] | wlws f32[2] | ticket u32
  unsigned char* zn8 = (unsigned char*)d_ws;
  float* rowpart = (float*)((char*)d_ws + (size_t)PN2 * PD);
  float* pos     = rowpart + (size_t)NBLK * PN2;
  float* wlws    = pos + PN2;
  unsigned* ticket = (unsigned*)(wlws + 2);

  normalize_kernel<<<PN / 4, 256, 0, stream>>>(zi, zj, zn8, pos, wlws, ticket);
  simsum_kernel<<<NTRI, 512, 0, stream>>>(zn8, rowpart);
  finalize_kernel<<<32, 256, 0, stream>>>(rowpart, pos, w, wlws, ticket, out);
}